// Round 1
// baseline (858.805 us; speedup 1.0000x reference)
//
#include <hip/hip_runtime.h>
#include <math.h>

#define Bn 16
#define Ln 2500
#define En 100
#define FM 50
#define Yn 8921
#define KS 10
#define LP 2501
#define NT 40   // 40 tiles of 64 l (2560 >= 2501)

typedef __attribute__((ext_vector_type(8))) short short8;
typedef __attribute__((ext_vector_type(4))) float f32x4;
typedef __attribute__((ext_vector_type(4))) int  i32x4;

union S8 { short8 v; long l2[2]; short s[8]; };
union I4 { i32x4 v; long l2[2]; };

__device__ __forceinline__ short f2bf(float f){
  unsigned u = __float_as_uint(f);
  unsigned r = (u + 0x7fffu + ((u >> 16) & 1u)) >> 16;
  return (short)r;
}

// ---------------- K0: transpose conv_w (Fm,E,K) -> WT[e*10+k][f(64 pad0)] ----------------
__global__ void k0_wt(const float* __restrict__ cw, float* __restrict__ WT){
  int i = blockIdx.x * 256 + threadIdx.x;
  if (i < 64000){
    int f = i & 63, ek = i >> 6;
    WT[i] = (f < FM) ? cw[f * 1000 + ek] : 0.f;
  }
}

// ---------------- K1: conv + bias + tanh -> H[b][t][l][64] bf16, HT[b][t][f][64] bf16 ----
__global__ __launch_bounds__(256) void k1_conv(
    const float* __restrict__ x, const float* __restrict__ WT,
    const float* __restrict__ conv_b,
    short* __restrict__ Hg, short* __restrict__ HTg)
{
  int t = blockIdx.x, b = blockIdx.y, tid = threadIdx.x;
  __shared__ float x_s[100 * 76];       // [e][row(73) pad 76]
  __shared__ short h_t[64 * 69];        // [l][f pad 69]

  int r0 = 64 * t - 5;
  for (int d = tid; d < 7300; d += 256){
    int row = d / 100, e = d - row * 100;
    int gr = r0 + row;
    float v = (gr >= 0 && gr < Ln) ? x[((size_t)b * Ln + gr) * 100 + e] : 0.f;
    x_s[e * 76 + row] = v;
  }
  __syncthreads();

  int f = tid & 63, lsub = tid >> 6;
  float acc[16];
#pragma unroll
  for (int j = 0; j < 16; j++) acc[j] = 0.f;

  for (int e = 0; e < 100; e++){
    float xv[25];
    const float* xr = x_s + e * 76 + lsub * 16;
#pragma unroll
    for (int i = 0; i < 6; i++){
      f32x4 q = *(const f32x4*)(xr + 4 * i);
      xv[4*i+0] = q[0]; xv[4*i+1] = q[1]; xv[4*i+2] = q[2]; xv[4*i+3] = q[3];
    }
    xv[24] = xr[24];
#pragma unroll
    for (int k = 0; k < KS; k++){
      float wv = WT[(e * 10 + k) * 64 + f];
#pragma unroll
      for (int j = 0; j < 16; j++) acc[j] += wv * xv[j + k];
    }
  }

  float bias = (f < FM) ? conv_b[f] : 0.f;
  size_t tb = ((size_t)(b * NT + t)) << 12;
#pragma unroll
  for (int j = 0; j < 16; j++){
    int l = lsub * 16 + j;
    int lgl = 64 * t + l;
    float hv = (lgl < LP && f < FM) ? tanhf(acc[j] + bias) : 0.f;
    short hb = f2bf(hv);
    Hg[tb + (size_t)l * 64 + f] = hb;
    h_t[l * 69 + f] = hb;
  }
  __syncthreads();
  int lane = tid & 63, wave = tid >> 6;
#pragma unroll
  for (int i = 0; i < 16; i++){
    int fo = wave + 4 * i;
    HTg[tb + (size_t)fo * 64 + lane] = h_t[lane * 69 + fo];
  }
}

// ---------------- K2 helpers ----------------
__device__ __forceinline__ void stage_tiles(const short* __restrict__ Hg_t,
                                            const short* __restrict__ HTg_t,
                                            short* __restrict__ h_s,
                                            short* __restrict__ ht_s, int tid)
{
  // h_s: [fs(4)][l(64)][20] (16 used) ; global H tile is [l][64]
  I4 v0, v1;
  v0.v = ((const i32x4*)Hg_t)[tid * 2];
  v1.v = ((const i32x4*)Hg_t)[tid * 2 + 1];
  {
    int l_ = tid >> 2, fs_ = tid & 3;
    short* dst = h_s + fs_ * 1280 + l_ * 20;
    *(long*)(dst + 0)  = v0.l2[0];
    *(long*)(dst + 4)  = v0.l2[1];
    *(long*)(dst + 8)  = v1.l2[0];
    *(long*)(dst + 12) = v1.l2[1];
  }
  // ht_s: [f(64)][72] ; global HT tile is [f][64]
  i32x4 w0 = ((const i32x4*)HTg_t)[tid * 2];
  i32x4 w1 = ((const i32x4*)HTg_t)[tid * 2 + 1];
  {
    short* d2 = ht_s + (tid >> 2) * 72 + (tid & 3) * 16;
    *(i32x4*)(d2)     = w0;
    *(i32x4*)(d2 + 8) = w1;
  }
}

__device__ __forceinline__ void scores_tile(const short* __restrict__ h_s,
                                            const S8 bu[2], int c, int g, f32x4 d[4])
{
#pragma unroll
  for (int ms = 0; ms < 4; ms++){
    f32x4 acc = {0.f, 0.f, 0.f, 0.f};
#pragma unroll
    for (int kf = 0; kf < 2; kf++){
      const short* pa = h_s + (2 * kf) * 1280 + (c + 16 * ms) * 20 + 4 * g;
      S8 a;
      a.l2[0] = *(const long*)pa;
      a.l2[1] = *(const long*)(pa + 1280);
      acc = __builtin_amdgcn_mfma_f32_16x16x32_bf16(a.v, bu[kf].v, acc, 0, 0, 0);
    }
    d[ms] = acc;
  }
}

// ---------------- K2: fused scores -> softmax -> alpha write -> m -> logits -------------
__global__ __launch_bounds__(256) void k2_attn(
    const short* __restrict__ Hg, const short* __restrict__ HTg,
    const float* __restrict__ U_w, const float* __restrict__ final_w,
    const float* __restrict__ final_b,
    float* __restrict__ logits, float* __restrict__ alpha_out)
{
  int b = blockIdx.y;
  int y0 = blockIdx.x * 64;
  int tid = threadIdx.x;
  int lane = tid & 63, wave = tid >> 6;
  int c = lane & 15, g = lane >> 4;
  int ywave = y0 + wave * 16;

  __shared__ __align__(16) short h_s[5120];
  __shared__ __align__(16) short ht_s[4608];
  __shared__ float alpha_s[4608];

  // B1 fragments from U_w (same k-slot convention as A fragments)
  S8 bu[2];
  {
    int yv = ywave + c;
#pragma unroll
    for (int kf = 0; kf < 2; kf++)
#pragma unroll
      for (int i = 0; i < 8; i++){
        int fidx = 4 * g + (i & 3) + 16 * (i >> 2) + 32 * kf;
        float v = (yv < Yn && fidx < FM) ? U_w[yv * FM + fidx] : 0.f;
        bu[kf].s[i] = f2bf(v);
      }
  }

  const size_t tb0 = ((size_t)(b * NT)) << 12;

  // ---- pass 1: online max/sum ----
  float M = -INFINITY, S = 0.f;
  for (int t = 0; t < NT; t++){
    __syncthreads();
    stage_tiles(Hg + tb0 + ((size_t)t << 12), HTg + tb0 + ((size_t)t << 12), h_s, ht_s, tid);
    __syncthreads();
    f32x4 d[4];
    scores_tile(h_s, bu, c, g, d);
    float vv[16];
    float tmax = -INFINITY;
#pragma unroll
    for (int ms = 0; ms < 4; ms++)
#pragma unroll
      for (int r = 0; r < 4; r++){
        int l = 64 * t + 16 * ms + 4 * g + r;
        float v = (l < LP) ? d[ms][r] : -INFINITY;
        vv[ms * 4 + r] = v;
        tmax = fmaxf(tmax, v);
      }
    float nM = fmaxf(M, tmax);
    S *= __expf(M - nM);
#pragma unroll
    for (int i = 0; i < 16; i++) S += __expf(vv[i] - nM);
    M = nM;
  }
  // combine across the 4 lane-groups (same y, different l subsets)
#pragma unroll
  for (int off = 16; off <= 32; off <<= 1){
    float Mo = __shfl_xor(M, off);
    float So = __shfl_xor(S, off);
    float nM = fmaxf(M, Mo);
    S = S * __expf(M - nM) + So * __expf(Mo - nM);
    M = nM;
  }
  float invS = 1.f / S;

  // ---- pass 2: recompute scores, alpha, write alpha, accumulate m ----
  f32x4 m2[4];
#pragma unroll
  for (int fs = 0; fs < 4; fs++) m2[fs] = (f32x4){0.f, 0.f, 0.f, 0.f};

  for (int t = 0; t < NT; t++){
    __syncthreads();
    stage_tiles(Hg + tb0 + ((size_t)t << 12), HTg + tb0 + ((size_t)t << 12), h_s, ht_s, tid);
    __syncthreads();
    f32x4 d[4];
    scores_tile(h_s, bu, c, g, d);
    float a[16];
#pragma unroll
    for (int ms = 0; ms < 4; ms++)
#pragma unroll
      for (int r = 0; r < 4; r++){
        int l = 64 * t + 16 * ms + 4 * g + r;
        a[ms * 4 + r] = (l < LP) ? __expf(d[ms][r] - M) * invS : 0.f;
      }
    // GEMM2: m += alpha * h   (A2 repacked in-lane from scores^T fragments)
#pragma unroll
    for (int kl = 0; kl < 2; kl++){
      S8 a2;
#pragma unroll
      for (int i = 0; i < 8; i++)
        a2.s[i] = f2bf(a[(2 * kl + (i >> 2)) * 4 + (i & 3)]);
#pragma unroll
      for (int fs = 0; fs < 4; fs++){
        const short* pb = ht_s + (16 * fs + c) * 72 + 4 * g + 32 * kl;
        S8 b2;
        b2.l2[0] = *(const long*)pb;
        b2.l2[1] = *(const long*)(pb + 16);
        m2[fs] = __builtin_amdgcn_mfma_f32_16x16x32_bf16(a2.v, b2.v, m2[fs], 0, 0, 0);
      }
    }
    // alpha -> LDS (transpose to [y][l]) -> coalesced global store
    float* aw = alpha_s + wave * 1152;
#pragma unroll
    for (int ms = 0; ms < 4; ms++)
#pragma unroll
      for (int r = 0; r < 4; r++)
        aw[c * 72 + 16 * ms + 4 * g + r] = a[ms * 4 + r];
    __syncthreads();
#pragma unroll
    for (int j = 0; j < 16; j++){
      int yj = ywave + j;
      int lgl = 64 * t + lane;
      if (yj < Yn && lgl < LP)
        alpha_out[((size_t)b * Yn + yj) * LP + lgl] = aw[j * 72 + lane];
    }
  }

  // ---- epilogue: logits[y] = sum_f final_w[y][f] * m[y][f] + final_b[y] ----
  float part[4];
#pragma unroll
  for (int r = 0; r < 4; r++){
    int yy = ywave + 4 * g + r;
    float p = 0.f;
    if (yy < Yn){
#pragma unroll
      for (int fs = 0; fs < 4; fs++){
        int fcol = fs * 16 + c;
        if (fcol < FM) p += m2[fs][r] * final_w[yy * FM + fcol];
      }
    }
#pragma unroll
    for (int off = 1; off <= 8; off <<= 1) p += __shfl_xor(p, off);
    part[r] = p;
  }
  if (c == 0){
#pragma unroll
    for (int r = 0; r < 4; r++){
      int yy = ywave + 4 * g + r;
      if (yy < Yn) logits[(size_t)b * Yn + yy] = part[r] + final_b[yy];
    }
  }
}

// ---------------- K3: log_softmax over Y + BCE loss partials ----------------
__global__ __launch_bounds__(256) void k3_lsm(
    const float* __restrict__ logits, const float* __restrict__ target,
    float* __restrict__ proba, float* __restrict__ lossp)
{
  int b = blockIdx.x, tid = threadIdx.x;
  int lane = tid & 63, wave = tid >> 6;
  __shared__ float red[4];
  const float* lg = logits + (size_t)b * Yn;
  const float* tg = target + (size_t)b * Yn;

  float m = -INFINITY;
  for (int y = tid; y < Yn; y += 256) m = fmaxf(m, lg[y]);
#pragma unroll
  for (int off = 1; off <= 32; off <<= 1) m = fmaxf(m, __shfl_xor(m, off));
  if (lane == 0) red[wave] = m;
  __syncthreads();
  m = fmaxf(fmaxf(red[0], red[1]), fmaxf(red[2], red[3]));
  __syncthreads();

  float s = 0.f;
  for (int y = tid; y < Yn; y += 256) s += __expf(lg[y] - m);
#pragma unroll
  for (int off = 1; off <= 32; off <<= 1) s += __shfl_xor(s, off);
  if (lane == 0) red[wave] = s;
  __syncthreads();
  s = red[0] + red[1] + red[2] + red[3];
  __syncthreads();
  float lse = m + logf(s);

  float ls = 0.f;
  for (int y = tid; y < Yn; y += 256){
    float xx = lg[y];
    proba[(size_t)b * Yn + y] = xx - lse;
    ls += fmaxf(xx, 0.f) - xx * tg[y] + log1pf(__expf(-fabsf(xx)));
  }
#pragma unroll
  for (int off = 1; off <= 32; off <<= 1) ls += __shfl_xor(ls, off);
  if (lane == 0) red[wave] = ls;
  __syncthreads();
  if (tid == 0) lossp[b] = red[0] + red[1] + red[2] + red[3];
}

__global__ void k4_loss(const float* __restrict__ lossp, float* __restrict__ out){
  if (threadIdx.x == 0){
    float s = 0.f;
    for (int i = 0; i < Bn; i++) s += lossp[i];
    out[142736] = s / 142736.f;
  }
}

// ---------------- launch ----------------
extern "C" void kernel_launch(void* const* d_in, const int* in_sizes, int n_in,
                              void* d_out, int out_size, void* d_ws, size_t ws_size,
                              hipStream_t stream)
{
  const float* x       = (const float*)d_in[0];
  const float* target  = (const float*)d_in[1];
  const float* conv_w  = (const float*)d_in[2];
  const float* conv_b  = (const float*)d_in[3];
  const float* U_w     = (const float*)d_in[4];
  const float* final_w = (const float*)d_in[5];
  const float* final_b = (const float*)d_in[6];
  float* out = (float*)d_out;

  char* ws = (char*)d_ws;
  short* Hg     = (short*)(ws);                 // 5,242,880 B
  short* HTg    = (short*)(ws + 5242880);       // 5,242,880 B
  float* WT     = (float*)(ws + 10485760);      //   256,000 B
  float* logits = (float*)(ws + 10741760);      //   570,944 B
  float* lossp  = (float*)(ws + 11312704);      //        64 B

  float* proba     = out;              // B*Y
  float* alpha_out = out + 142737;     // after proba + loss

  k0_wt<<<dim3(250), dim3(256), 0, stream>>>(conv_w, WT);
  k1_conv<<<dim3(NT, Bn), dim3(256), 0, stream>>>(x, WT, conv_b, Hg, HTg);
  k2_attn<<<dim3(140, Bn), dim3(256), 0, stream>>>(Hg, HTg, U_w, final_w, final_b,
                                                   logits, alpha_out);
  k3_lsm<<<dim3(Bn), dim3(256), 0, stream>>>(logits, target, proba, lossp);
  k4_loss<<<dim3(1), dim3(64), 0, stream>>>(lossp, out);
}